// Round 12
// baseline (169.345 us; speedup 1.0000x reference)
//
#include <hip/hip_runtime.h>
#include <hip/hip_fp16.h>

#define N_NODES 50000
#define EPS 1e-6f
#define NPAD 50048      // N rounded up to 64
#define CAP 64          // fixed per-node neighbor capacity (max real deg ~45, Poisson(16))

// ---- Two-pass radix build geometry (round-13) ----
#define NBKT 512        // buckets
#define NPB 98          // nodes per bucket; NBKT*NPB = 50176 >= NPAD
#define NROWS (NBKT * NPB)
#define BCAP 2048       // per-bucket edge capacity (= 1<<11); expected 1568, +12 sigma
#define CHUNK_A 3072    // edges per bucketize block -> 261 blocks (grid contract: >=256)
#define XH8 (N_NODES * 64 / 8)   // uint4-granules of the x->half conversion

// ---------------- Workspace layout (ints then halves then floats) ----------------
// bcur   : NBKT ints      (zeroed each call)
// packed : NBKT*BCAP ints ((src<<8)|dlocal, grouped by bucket)
// cnt    : NROWS ints     (per-node degree)
// ssrc   : NROWS*64 ints  (fixed-stride per-node neighbor lists; gather2 input)
// mean1h : NPAD*64 halves (fp16 staging of layer-1 mean)
// xh     : NPAD*64 halves (fp16 staging of x)
// gh     : NPAD*64 halves (fp16 staging of layer-2 pre-gather features)
// valA   : NPAD*32 floats (gather2 pass-A partial val, features 0..31)
//
// NUMERICS CONTRACT (r18/19/21/23): absmax pinned 0.03125 (1 ulp of the
// bf16 output comparison). fp16 staging of gather operands and fp16-W
// f32-accum MFMA GEMMs measured-invisible. Gather ADD SEQUENCE per
// feature unchanged: groups-of-4 (v0+v1)+(v2+v3) ascending, tail
// sequential, f32 after cvt. Round-23 feature-split permutes WHICH lane
// slot holds which feature in the softmax butterfly (same 8,4,2,1 +
// (x+z)+(y+w) shape) — f32-ulp-level perturbation only.
//    mean = acc*dinv, dinv = 1/(deg+EPS); val = acc*dinv + b2;
// MFMA LAYOUT (round-21, verified): A/B frags contiguous-k, lane holds
// k=(lane>>4)*8+i via ds_read_b128 from row-major [m][k]/[n][k] tiles;
// C/D col=lane&15, row=(lane>>4)*4+reg. LDS strides%32banks==4.
// SCHEDULE CONTRACT (round-6): constant-trip k-loops with global loads
// carry #pragma unroll 1 (f32 path; MFMA loops are LDS-only, exempt).
// GATHER CONTRACT (round-8): NO per-edge LDS atomics in float gathers.
// GRID CONTRACT (round-9/20): build kernels >=256 blocks; gathers use
// per-tile grids — persistent grid-stride REGRESSED (round-20).
// BUILD CONTRACT (round-13): no scattered 4B global writes.
// FUSION CONTRACT (round-14/22): no gather behind barrier-blocked GEMM;
// rows+gather1 trailing-phase fusion kept (round-22, small win).
// BATCH CONTRACT (round-16/17): branchless 16-load gather step; pad slots
// clamp index to row 0; uniform-predicate adds, compile-time indices.
// MACRO CONTRACT (round-17): multi-statement macros are do{...}while(0).
// PRECISION CONTRACT (round-18): fp16 staging (NOT bf16).
// CONCURRENCY MODEL (round-20/23): gathers are capped at ~51-64
// outstanding 64B lines/CU; throughput = cap*64B/latency. At L3 latency
// (~900cy, working set > 4MB L2/XCD) => ~37us/gather — matches measured.
// Round-23 lever: FEATURE-SPLIT passes with <=3.2MB working set each =>
// L2-resident => L2-hit latency => ~4x line rate. Split only gather2
// this round (single-variable attribution).

#define COMP(v, j) ((j) == 0 ? (v).x : (j) == 1 ? (v).y : (j) == 2 ? (v).z : (v).w)

typedef _Float16 half8 __attribute__((ext_vector_type(8)));
typedef float floatx4 __attribute__((ext_vector_type(4)));

__device__ __forceinline__ float4 h4_to_f4(uint2 u) {
  __half2 h0 = *reinterpret_cast<__half2*>(&u.x);
  __half2 h1 = *reinterpret_cast<__half2*>(&u.y);
  float2 f0 = __half22float2(h0);
  float2 f1 = __half22float2(h1);
  float4 r; r.x = f0.x; r.y = f0.y; r.z = f1.x; r.w = f1.y;
  return r;
}

__device__ __forceinline__ float2 h2_to_f2(unsigned int u) {
  __half2 h = *reinterpret_cast<__half2*>(&u);
  return __half22float2(h);
}

// ---- Pass A: partition edges into 512 buckets of 98 nodes ----
// (also converts x -> xh fp16 staging, grid-stride)
__global__ __launch_bounds__(256) void bucketize_kernel(
    const int* __restrict__ src, const int* __restrict__ dst,
    int* __restrict__ bcur, int* __restrict__ packed,
    const float* __restrict__ x, __half* __restrict__ xh, int E) {
  __shared__ int lcnt[NBKT];
  __shared__ int lbase[NBKT];
  int t = threadIdx.x;

  for (int i = blockIdx.x * 256 + t; i < XH8; i += gridDim.x * 256) {
    float4 a = ((const float4*)x)[2 * i];
    float4 b = ((const float4*)x)[2 * i + 1];
    __half2 h0 = __floats2half2_rn(a.x, a.y);
    __half2 h1 = __floats2half2_rn(a.z, a.w);
    __half2 h2 = __floats2half2_rn(b.x, b.y);
    __half2 h3 = __floats2half2_rn(b.z, b.w);
    uint4 o;
    o.x = *(unsigned int*)&h0; o.y = *(unsigned int*)&h1;
    o.z = *(unsigned int*)&h2; o.w = *(unsigned int*)&h3;
    ((uint4*)xh)[i] = o;
  }

  lcnt[t] = 0; lcnt[t + 256] = 0;
  __syncthreads();
  int base = blockIdx.x * CHUNK_A;
  int end = base + CHUNK_A; if (end > E) end = E;
  for (int e = base + t; e < end; e += 256) atomicAdd(&lcnt[dst[e] / NPB], 1);
  __syncthreads();
  {
    int c0 = lcnt[t], c1 = lcnt[t + 256];
    lbase[t]       = c0 ? atomicAdd(&bcur[t], c0) : 0;
    lbase[t + 256] = c1 ? atomicAdd(&bcur[t + 256], c1) : 0;
    lcnt[t] = 0; lcnt[t + 256] = 0;
  }
  __syncthreads();
  for (int e = base + t; e < end; e += 256) {
    int d = dst[e];
    int b = d / NPB;
    int pos = lbase[b] + atomicAdd(&lcnt[b], 1);
    if (pos < BCAP)
      packed[(b << 11) + pos] = (src[e] << 8) | (d - b * NPB);
  }
}

// Quad add in contract order (per component: one quad at a time, ascending).
#define QADD(V0, V1, V2, V3) do {                                         \
    acc.x += ((V0).x + (V1).x) + ((V2).x + (V3).x);                       \
    acc.y += ((V0).y + (V1).y) + ((V2).y + (V3).y);                       \
    acc.z += ((V0).z + (V1).z) + ((V2).z + (V3).z);                       \
    acc.w += ((V0).w + (V1).w) + ((V2).w + (V3).w);                       \
  } while (0)

#define ADD1(V) do {                                                      \
    acc.x += (V).x; acc.y += (V).y; acc.z += (V).z; acc.w += (V).w;       \
  } while (0)

#define QADD2(F0, F1, F2, F3) do {                                        \
    acc.x += ((F0).x + (F1).x) + ((F2).x + (F3).x);                       \
    acc.y += ((F0).y + (F1).y) + ((F2).y + (F3).y);                       \
  } while (0)

#define ADD1_2(F) do { acc.x += (F).x; acc.y += (F).y; } while (0)

// Row-load + contract-order accumulate given index array s[16] and rem.
// Full-row (8B/lane, fp16 x4) variant.
#define GATHER_BODY_H(SRCPTR)                                             \
  do {                                                                    \
    uint2 v[16];                                                          \
    _Pragma("unroll")                                                     \
    for (int j = 0; j < 16; j++)                                          \
      v[j] = ((const uint2*)((SRCPTR) + (size_t)s[j] * 64))[l16];         \
    int rq = rem >> 2, rr = rem & 3;                                      \
    _Pragma("unroll")                                                     \
    for (int q = 0; q < 4; q++) {                                         \
      if (q < rq) {                                                       \
        float4 f0 = h4_to_f4(v[4 * q]);                                   \
        float4 f1 = h4_to_f4(v[4 * q + 1]);                               \
        float4 f2 = h4_to_f4(v[4 * q + 2]);                               \
        float4 f3 = h4_to_f4(v[4 * q + 3]);                               \
        QADD(f0, f1, f2, f3);                                             \
      }                                                                   \
    }                                                                     \
    _Pragma("unroll")                                                     \
    for (int q = 0; q < 4; q++) {                                         \
      if (q == rq && rr > 0) {                                            \
        float4 f0 = h4_to_f4(v[4 * q]);                                   \
        ADD1(f0);                                                         \
        if (rr > 1) { float4 f1 = h4_to_f4(v[4 * q + 1]); ADD1(f1); }     \
        if (rr > 2) { float4 f2 = h4_to_f4(v[4 * q + 2]); ADD1(f2); }     \
      }                                                                   \
    }                                                                     \
  } while (0)

// Half-row (4B/lane, fp16 x2, one 64B line per row) variant. HOFF in halves.
#define GATHER_BODY_H2(SRCPTR, HOFF)                                      \
  do {                                                                    \
    unsigned int v[16];                                                   \
    _Pragma("unroll")                                                     \
    for (int j = 0; j < 16; j++)                                          \
      v[j] = ((const unsigned int*)((SRCPTR) + (size_t)s[j] * 64 + (HOFF)))[l16]; \
    int rq = rem >> 2, rr = rem & 3;                                      \
    _Pragma("unroll")                                                     \
    for (int q = 0; q < 4; q++) {                                         \
      if (q < rq) {                                                       \
        float2 f0 = h2_to_f2(v[4 * q]);                                   \
        float2 f1 = h2_to_f2(v[4 * q + 1]);                               \
        float2 f2 = h2_to_f2(v[4 * q + 2]);                               \
        float2 f3 = h2_to_f2(v[4 * q + 3]);                               \
        QADD2(f0, f1, f2, f3);                                            \
      }                                                                   \
    }                                                                     \
    _Pragma("unroll")                                                     \
    for (int q = 0; q < 4; q++) {                                         \
      if (q == rq && rr > 0) {                                            \
        float2 f0 = h2_to_f2(v[4 * q]);                                   \
        ADD1_2(f0);                                                       \
        if (rr > 1) { float2 f1 = h2_to_f2(v[4 * q + 1]); ADD1_2(f1); }   \
        if (rr > 2) { float2 f2 = h2_to_f2(v[4 * q + 2]); ADD1_2(f2); }   \
      }                                                                   \
    }                                                                     \
  } while (0)

// ---- Pass B + gather1 fused: build rows, store ssrc/cnt, then gather
// means for this bucket's nodes with indices read from the LDS row image.
__global__ __launch_bounds__(256) void rows_gather1_kernel(
    const int* __restrict__ bcur, const int* __restrict__ packed,
    int* __restrict__ cnt, int* __restrict__ ssrc,
    const __half* __restrict__ xh, __half* __restrict__ mean1h) {
  __shared__ int lout[NPB * 64];
  __shared__ int lcnt[NPB];
  int t = threadIdx.x;
  int b = blockIdx.x;
  if (t < NPB) lcnt[t] = 0;
  __syncthreads();
  int count = bcur[b]; if (count > BCAP) count = BCAP;
  const int* pk = packed + (b << 11);
  for (int i = t; i < count; i += 256) {
    int p = pk[i];
    int dl = p & 0xff;
    int pos = atomicAdd(&lcnt[dl], 1);
    if (pos < CAP) lout[(dl << 6) + pos] = p >> 8;
  }
  __syncthreads();
  {
    int4* d4 = (int4*)(ssrc + (size_t)b * (NPB * 64));
    const int4* s4 = (const int4*)lout;
    for (int i = t; i < NPB * 16; i += 256) d4[i] = s4[i];
    if (t < NPB) {
      int c = lcnt[t]; if (c > CAP) c = CAP;
      cnt[b * NPB + t] = c;
    }
  }
  int sg = t >> 4;
  int l16 = t & 15;
  for (int dl = sg; dl < NPB; dl += 16) {
    int node = b * NPB + dl;
    if (node >= N_NODES) continue;
    int deg = lcnt[dl]; if (deg > CAP) deg = CAP;
    const int* lrow = &lout[dl << 6];
    float4 acc = {0.f, 0.f, 0.f, 0.f};
    for (int base = 0; base < deg; base += 16) {
      int rem = deg - base; if (rem > 16) rem = 16;
      int s[16];
#pragma unroll
      for (int j = 0; j < 16; j++) s[j] = lrow[base + j];  // LDS broadcast
#pragma unroll
      for (int j = 0; j < 16; j++) { if (j >= rem) s[j] = 0; }
      GATHER_BODY_H(xh);
    }
    float dinv = 1.0f / ((float)deg + EPS);
    __half2 p0 = __floats2half2_rn(acc.x * dinv, acc.y * dinv);
    __half2 p1 = __floats2half2_rn(acc.z * dinv, acc.w * dinv);
    uint2 o;
    o.x = *(unsigned int*)&p0; o.y = *(unsigned int*)&p1;
    ((uint2*)(mean1h + (size_t)node * 64))[l16] = o;
  }
}

// ---- MFMA MLP: GEMM1(64x64x128)+relu -> GEMM2(64x128x64), fp16 out ----
__global__ __launch_bounds__(256) void mlp_mfma_kernel(
    const __half* __restrict__ mean1h, const float* __restrict__ W1,
    const float* __restrict__ b1, const float* __restrict__ W2,
    __half* __restrict__ gh) {
  __shared__ __align__(16) char smem[62464];
  __half (*sM)[72]    = (__half(*)[72])smem;
  __half (*sW1T)[72]  = (__half(*)[72])(smem + 9216);
  __half (*sH)[136]   = (__half(*)[136])(smem + 27648);
  __half (*sW2T)[136] = (__half(*)[136])(smem + 45056);
  __half (*sG)[64]    = (__half(*)[64])smem;

  int t = threadIdx.x;
  int row0 = blockIdx.x * 64;

  {
    const uint4* M4 = (const uint4*)(mean1h + (size_t)row0 * 64);
#pragma unroll
    for (int i = 0; i < 2; i++) {
      int idx = t + 256 * i;
      uint4 v = M4[idx];
      *(uint4*)&sM[idx >> 3][(idx & 7) * 8] = v;
    }
  }
#pragma unroll
  for (int i = 0; i < 8; i++) {
    int idx = t + 256 * i;
    int k = idx >> 5, c4 = (idx & 31) * 4;
    float4 w = *(const float4*)(W1 + (size_t)k * 128 + c4);
    sW1T[c4 + 0][k] = __float2half(w.x);
    sW1T[c4 + 1][k] = __float2half(w.y);
    sW1T[c4 + 2][k] = __float2half(w.z);
    sW1T[c4 + 3][k] = __float2half(w.w);
  }
#pragma unroll
  for (int i = 0; i < 8; i++) {
    int idx = t + 256 * i;
    int k = idx >> 4, c4 = (idx & 15) * 4;
    float4 w = *(const float4*)(W2 + (size_t)k * 64 + c4);
    sW2T[c4 + 0][k] = __float2half(w.x);
    sW2T[c4 + 1][k] = __float2half(w.y);
    sW2T[c4 + 2][k] = __float2half(w.z);
    sW2T[c4 + 3][k] = __float2half(w.w);
  }
  __syncthreads();

  int l = t & 63, wv = t >> 6;
  int l16 = l & 15, lg = l >> 4;

  {  // GEMM1
    floatx4 acc[4][2];
#pragma unroll
    for (int tc = 0; tc < 2; tc++) {
      float bias = b1[(2 * wv + tc) * 16 + l16];
#pragma unroll
      for (int tr = 0; tr < 4; tr++)
        acc[tr][tc] = (floatx4){bias, bias, bias, bias};
    }
#pragma unroll
    for (int kb = 0; kb < 2; kb++) {
      half8 a[4], bf[2];
#pragma unroll
      for (int tr = 0; tr < 4; tr++)
        a[tr] = *(const half8*)&sM[tr * 16 + l16][kb * 32 + lg * 8];
#pragma unroll
      for (int tc = 0; tc < 2; tc++)
        bf[tc] = *(const half8*)&sW1T[(2 * wv + tc) * 16 + l16][kb * 32 + lg * 8];
#pragma unroll
      for (int tc = 0; tc < 2; tc++)
#pragma unroll
        for (int tr = 0; tr < 4; tr++)
          acc[tr][tc] = __builtin_amdgcn_mfma_f32_16x16x32_f16(
              a[tr], bf[tc], acc[tr][tc], 0, 0, 0);
    }
#pragma unroll
    for (int tc = 0; tc < 2; tc++)
#pragma unroll
      for (int tr = 0; tr < 4; tr++)
#pragma unroll
        for (int r = 0; r < 4; r++) {
          float h = fmaxf(acc[tr][tc][r], 0.f);
          sH[tr * 16 + lg * 4 + r][(2 * wv + tc) * 16 + l16] = __float2half(h);
        }
  }
  __syncthreads();

  {  // GEMM2
    floatx4 acc[4];
#pragma unroll
    for (int tc = 0; tc < 4; tc++) acc[tc] = (floatx4){0.f, 0.f, 0.f, 0.f};
    half8 a[4];
#pragma unroll
    for (int kb = 0; kb < 4; kb++)
      a[kb] = *(const half8*)&sH[wv * 16 + l16][kb * 32 + lg * 8];
#pragma unroll
    for (int tc = 0; tc < 4; tc++) {
#pragma unroll
      for (int kb = 0; kb < 4; kb++) {
        half8 bf = *(const half8*)&sW2T[tc * 16 + l16][kb * 32 + lg * 8];
        acc[tc] = __builtin_amdgcn_mfma_f32_16x16x32_f16(a[kb], bf, acc[tc], 0, 0, 0);
      }
    }
#pragma unroll
    for (int tc = 0; tc < 4; tc++)
#pragma unroll
      for (int r = 0; r < 4; r++)
        sG[wv * 16 + lg * 4 + r][tc * 16 + l16] = __float2half(acc[tc][r]);
  }
  __syncthreads();

#pragma unroll
  for (int i = 0; i < 4; i++) {
    int idx = t + 256 * i;
    int row = idx >> 4, c4 = (idx & 15) * 4;
    if (row0 + row < N_NODES)
      *(uint2*)(gh + (size_t)(row0 + row) * 64 + c4) = *(uint2*)&sG[row][c4];
  }
}

// ---- Gather 2, pass A: features 0..31 (first 64B line of each gh row) ----
__global__ __launch_bounds__(256) void gather2a_kernel(
    const __half* __restrict__ gh, const int* __restrict__ cnt,
    const int* __restrict__ ssrc, const float* __restrict__ b2,
    float* __restrict__ valA) {
  int t = threadIdx.x;
  int lane = t & 63;
  int sub = lane >> 4;
  int l16 = lane & 15;
  int node = blockIdx.x * 16 + ((t >> 6) << 2) + sub;
  int b = node << 6;
  int e = b + cnt[node];
  float2 acc = {0.f, 0.f};
  for (int base = b; base < e; base += 16) {
    int rem = e - base; if (rem > 16) rem = 16;
    int s[16];
#pragma unroll
    for (int j = 0; j < 16; j++) s[j] = ssrc[base + j];
#pragma unroll
    for (int j = 0; j < 16; j++) { if (j >= rem) s[j] = 0; }
    GATHER_BODY_H2(gh, 0);
  }
  float dinv = 1.0f / ((float)(e - b) + EPS);
  float2 b2v = *(const float2*)(b2 + l16 * 2);
  float2 val;
  val.x = acc.x * dinv + b2v.x;
  val.y = acc.y * dinv + b2v.y;
  ((float2*)(valA + (size_t)node * 32))[l16] = val;
}

// ---- Gather 2, pass B: features 32..63 + pass-A partials + log_softmax ----
__global__ __launch_bounds__(256) void gather2b_kernel(
    const __half* __restrict__ gh, const int* __restrict__ cnt,
    const int* __restrict__ ssrc, const float* __restrict__ b2,
    const float* __restrict__ valA, float* __restrict__ out) {
  int t = threadIdx.x;
  int lane = t & 63;
  int sub = lane >> 4;
  int l16 = lane & 15;
  int node = blockIdx.x * 16 + ((t >> 6) << 2) + sub;
  int b = node << 6;
  int e = b + cnt[node];
  float2 acc = {0.f, 0.f};
  for (int base = b; base < e; base += 16) {
    int rem = e - base; if (rem > 16) rem = 16;
    int s[16];
#pragma unroll
    for (int j = 0; j < 16; j++) s[j] = ssrc[base + j];
#pragma unroll
    for (int j = 0; j < 16; j++) { if (j >= rem) s[j] = 0; }
    GATHER_BODY_H2(gh, 32);
  }
  float dinv = 1.0f / ((float)(e - b) + EPS);
  float2 b2v = *(const float2*)(b2 + 32 + l16 * 2);
  float2 own;
  own.x = acc.x * dinv + b2v.x;
  own.y = acc.y * dinv + b2v.y;
  float2 pA = ((const float2*)(valA + (size_t)node * 32))[l16];
  // val slots: x,y = features l16*2,l16*2+1 ; z,w = 32+l16*2, 32+l16*2+1
  float4 val; val.x = pA.x; val.y = pA.y; val.z = own.x; val.w = own.y;

  float4 m = val;
#pragma unroll
  for (int o = 8; o > 0; o >>= 1) {
    m.x = fmaxf(m.x, __shfl_xor(m.x, o, 64));
    m.y = fmaxf(m.y, __shfl_xor(m.y, o, 64));
    m.z = fmaxf(m.z, __shfl_xor(m.z, o, 64));
    m.w = fmaxf(m.w, __shfl_xor(m.w, o, 64));
  }
  float mx = fmaxf(fmaxf(m.x, m.z), fmaxf(m.y, m.w));

  float4 ex;
  ex.x = __expf(val.x - mx);
  ex.y = __expf(val.y - mx);
  ex.z = __expf(val.z - mx);
  ex.w = __expf(val.w - mx);
#pragma unroll
  for (int o = 8; o > 0; o >>= 1) {
    ex.x += __shfl_xor(ex.x, o, 64);
    ex.y += __shfl_xor(ex.y, o, 64);
    ex.z += __shfl_xor(ex.z, o, 64);
    ex.w += __shfl_xor(ex.w, o, 64);
  }
  float sm = (ex.x + ex.z) + (ex.y + ex.w);

  float ls = logf(sm);
  float2 o0, o1;
  o0.x = (val.x - mx) - ls;
  o0.y = (val.y - mx) - ls;
  o1.x = (val.z - mx) - ls;
  o1.y = (val.w - mx) - ls;
  ((float2*)(out + (size_t)node * 64))[l16] = o0;
  ((float2*)(out + (size_t)node * 64 + 32))[l16] = o1;
}

extern "C" void kernel_launch(void* const* d_in, const int* in_sizes, int n_in,
                              void* d_out, int out_size, void* d_ws, size_t ws_size,
                              hipStream_t stream) {
  const float* x   = (const float*)d_in[0];
  const int*   src = (const int*)d_in[1];
  const int*   dst = (const int*)d_in[2];
  const float* W1  = (const float*)d_in[3];
  const float* b1  = (const float*)d_in[4];
  const float* W2  = (const float*)d_in[5];
  const float* b2  = (const float*)d_in[6];
  float* out = (float*)d_out;
  int E = in_sizes[1];

  int* bcur   = (int*)d_ws;                         // NBKT
  int* packed = bcur + NBKT;                        // NBKT*BCAP
  int* cnt    = packed + (size_t)NBKT * BCAP;       // NROWS
  int* ssrc   = cnt + NROWS;                        // NROWS*64
  __half* mean1h = (__half*)(ssrc + (size_t)NROWS * 64); // NPAD*64 halves
  __half* xh   = mean1h + (size_t)NPAD * 64;             // NPAD*64 halves
  __half* gh   = xh + (size_t)NPAD * 64;                 // NPAD*64 halves
  float* valA  = (float*)(gh + (size_t)NPAD * 64);       // NPAD*32 floats

  hipMemsetAsync(bcur, 0, NBKT * sizeof(int), stream);
  bucketize_kernel<<<(E + CHUNK_A - 1) / CHUNK_A, 256, 0, stream>>>(
      src, dst, bcur, packed, x, xh, E);
  rows_gather1_kernel<<<NBKT, 256, 0, stream>>>(bcur, packed, cnt, ssrc, xh, mean1h);
  mlp_mfma_kernel<<<NPAD / 64, 256, 0, stream>>>(mean1h, W1, b1, W2, gh);
  gather2a_kernel<<<N_NODES / 16, 256, 0, stream>>>(gh, cnt, ssrc, b2, valA);
  gather2b_kernel<<<N_NODES / 16, 256, 0, stream>>>(gh, cnt, ssrc, b2, valA, out);
}

// Round 13
// 159.541 us; speedup vs baseline: 1.0614x; 1.0614x over previous
//
#include <hip/hip_runtime.h>
#include <hip/hip_fp16.h>

#define N_NODES 50000
#define EPS 1e-6f
#define NPAD 50048      // N rounded up to 64
#define CAP 64          // fixed per-node neighbor capacity (max real deg ~45, Poisson(16))

// ---- Two-pass radix build geometry (round-13) ----
#define NBKT 512        // buckets
#define NPB 98          // nodes per bucket; NBKT*NPB = 50176 >= NPAD
#define NROWS (NBKT * NPB)
#define BCAP 2048       // per-bucket edge capacity (= 1<<11); expected 1568, +12 sigma
#define CHUNK_A 3072    // edges per bucketize block -> 261 blocks (grid contract: >=256)
#define XH8 (N_NODES * 64 / 8)   // uint4-granules of the x->half conversion

// ---------------- Workspace layout (ints then halves) ----------------
// bcur   : NBKT ints      (zeroed each call)
// packed : NBKT*BCAP ints ((src<<8)|dlocal, grouped by bucket)
// cnt    : NROWS ints     (per-node degree)
// ssrc   : NROWS*64 ints  (fixed-stride per-node neighbor lists; gather2 input)
// mean1h : NPAD*64 halves (fp16 staging of layer-1 mean)
// xh     : NPAD*64 halves (fp16 staging of x)
// gh     : NPAD*64 halves (fp16 staging of layer-2 pre-gather features)
//
// NUMERICS CONTRACT (r18/19/21): absmax pinned 0.03125 (= 1 ulp of the
// bf16 output comparison). fp16 staging of gather operands (x, mean1, g)
// measured-invisible. f32-accum MFMA GEMMs with fp16 W1/W2/H (round-21,
// measured-invisible). Gather ADD SEQUENCE unchanged: groups-of-4
// (v0+v1)+(v2+v3) ascending, tail sequential, f32 after cvt.
//    mean = acc*dinv, dinv = 1/(deg+EPS); val = acc*dinv + b2;
//    softmax: lane-xor butterfly 8,4,2,1 then (x+z)+(y+w); (val-mx)-logf(sm).
// MFMA LAYOUT (round-21, verified): A/B frags contiguous-k, lane holds
// k=(lane>>4)*8+i via ds_read_b128 from row-major [m][k]/[n][k] tiles;
// C/D col=lane&15, row=(lane>>4)*4+reg. LDS strides%32banks==4.
// SCHEDULE CONTRACT (round-6): constant-trip k-loops with global loads
// carry #pragma unroll 1 (f32 path; MFMA loops are LDS-only, exempt).
// GATHER CONTRACT (round-8): NO per-edge LDS atomics in float gathers.
// GRID CONTRACT (round-9/20): build kernels >=256 blocks; gathers use
// per-tile grids — persistent grid-stride REGRESSED (round-20).
// BUILD CONTRACT (round-13): no scattered 4B global writes.
// FUSION CONTRACT (round-14/22): no gather behind barrier-blocked GEMM
// (round-14, -8us); rows+gather1 trailing-phase fusion kept (round-22).
// BATCH CONTRACT (round-16/17): branchless 16-load gather step; pad slots
// clamp index to row 0; uniform-predicate adds, compile-time indices.
// MACRO CONTRACT (round-17): multi-statement macros are do{...}while(0).
// PRECISION CONTRACT (round-18): fp16 staging (NOT bf16). fp8 rows are
// numerically infeasible (e4m3 6% rel err on O(5) gh -> >0.093 absmax).
// CONCURRENCY MODEL (round-20/23/24 FINAL): gathers are capped at a
// chip-wide random-line throughput of ~24 64B-lines/cyc (~50-60
// outstanding lines/CU at L3-class latency). Tested and closed:
// fp16 line-halving WON (-18us); branchless step small win; shfl-removal
// neutral; persistent blocks REGRESSED; predicated loads REGRESSED;
// feature-split L2-residency passes REGRESSED (round-23: same line
// count, residency defeated by ssrc/valA streaming evictions, +11us).
// Gathers are at ~1.25x their 28us/gather structural floor. Do not
// touch the gather step again without a NEW line-count lever.

#define COMP(v, j) ((j) == 0 ? (v).x : (j) == 1 ? (v).y : (j) == 2 ? (v).z : (v).w)

typedef _Float16 half8 __attribute__((ext_vector_type(8)));
typedef float floatx4 __attribute__((ext_vector_type(4)));

__device__ __forceinline__ float4 h4_to_f4(uint2 u) {
  __half2 h0 = *reinterpret_cast<__half2*>(&u.x);
  __half2 h1 = *reinterpret_cast<__half2*>(&u.y);
  float2 f0 = __half22float2(h0);
  float2 f1 = __half22float2(h1);
  float4 r; r.x = f0.x; r.y = f0.y; r.z = f1.x; r.w = f1.y;
  return r;
}

// ---- Pass A: partition edges into 512 buckets of 98 nodes ----
// (also converts x -> xh fp16 staging, grid-stride)
__global__ __launch_bounds__(256) void bucketize_kernel(
    const int* __restrict__ src, const int* __restrict__ dst,
    int* __restrict__ bcur, int* __restrict__ packed,
    const float* __restrict__ x, __half* __restrict__ xh, int E) {
  __shared__ int lcnt[NBKT];
  __shared__ int lbase[NBKT];
  int t = threadIdx.x;

  for (int i = blockIdx.x * 256 + t; i < XH8; i += gridDim.x * 256) {
    float4 a = ((const float4*)x)[2 * i];
    float4 b = ((const float4*)x)[2 * i + 1];
    __half2 h0 = __floats2half2_rn(a.x, a.y);
    __half2 h1 = __floats2half2_rn(a.z, a.w);
    __half2 h2 = __floats2half2_rn(b.x, b.y);
    __half2 h3 = __floats2half2_rn(b.z, b.w);
    uint4 o;
    o.x = *(unsigned int*)&h0; o.y = *(unsigned int*)&h1;
    o.z = *(unsigned int*)&h2; o.w = *(unsigned int*)&h3;
    ((uint4*)xh)[i] = o;
  }

  lcnt[t] = 0; lcnt[t + 256] = 0;
  __syncthreads();
  int base = blockIdx.x * CHUNK_A;
  int end = base + CHUNK_A; if (end > E) end = E;
  for (int e = base + t; e < end; e += 256) atomicAdd(&lcnt[dst[e] / NPB], 1);
  __syncthreads();
  {
    int c0 = lcnt[t], c1 = lcnt[t + 256];
    lbase[t]       = c0 ? atomicAdd(&bcur[t], c0) : 0;
    lbase[t + 256] = c1 ? atomicAdd(&bcur[t + 256], c1) : 0;
    lcnt[t] = 0; lcnt[t + 256] = 0;
  }
  __syncthreads();
  for (int e = base + t; e < end; e += 256) {
    int d = dst[e];
    int b = d / NPB;
    int pos = lbase[b] + atomicAdd(&lcnt[b], 1);
    if (pos < BCAP)
      packed[(b << 11) + pos] = (src[e] << 8) | (d - b * NPB);
  }
}

// Quad add in contract order (per component: one quad at a time, ascending).
#define QADD(V0, V1, V2, V3) do {                                         \
    acc.x += ((V0).x + (V1).x) + ((V2).x + (V3).x);                       \
    acc.y += ((V0).y + (V1).y) + ((V2).y + (V3).y);                       \
    acc.z += ((V0).z + (V1).z) + ((V2).z + (V3).z);                       \
    acc.w += ((V0).w + (V1).w) + ((V2).w + (V3).w);                       \
  } while (0)

#define ADD1(V) do {                                                      \
    acc.x += (V).x; acc.y += (V).y; acc.z += (V).z; acc.w += (V).w;       \
  } while (0)

// Row-load + contract-order accumulate given index array s[16] and rem.
#define GATHER_BODY_H(SRCPTR)                                             \
  do {                                                                    \
    uint2 v[16];                                                          \
    _Pragma("unroll")                                                     \
    for (int j = 0; j < 16; j++)                                          \
      v[j] = ((const uint2*)((SRCPTR) + (size_t)s[j] * 64))[l16];         \
    int rq = rem >> 2, rr = rem & 3;                                      \
    _Pragma("unroll")                                                     \
    for (int q = 0; q < 4; q++) {                                         \
      if (q < rq) {                                                       \
        float4 f0 = h4_to_f4(v[4 * q]);                                   \
        float4 f1 = h4_to_f4(v[4 * q + 1]);                               \
        float4 f2 = h4_to_f4(v[4 * q + 2]);                               \
        float4 f3 = h4_to_f4(v[4 * q + 3]);                               \
        QADD(f0, f1, f2, f3);                                             \
      }                                                                   \
    }                                                                     \
    _Pragma("unroll")                                                     \
    for (int q = 0; q < 4; q++) {                                         \
      if (q == rq && rr > 0) {                                            \
        float4 f0 = h4_to_f4(v[4 * q]);                                   \
        ADD1(f0);                                                         \
        if (rr > 1) { float4 f1 = h4_to_f4(v[4 * q + 1]); ADD1(f1); }     \
        if (rr > 2) { float4 f2 = h4_to_f4(v[4 * q + 2]); ADD1(f2); }     \
      }                                                                   \
    }                                                                     \
  } while (0)

// ---- Pass B + gather1 fused: build rows, store ssrc/cnt, then gather
// means for this bucket's nodes with indices read from the LDS row image.
__global__ __launch_bounds__(256) void rows_gather1_kernel(
    const int* __restrict__ bcur, const int* __restrict__ packed,
    int* __restrict__ cnt, int* __restrict__ ssrc,
    const __half* __restrict__ xh, __half* __restrict__ mean1h) {
  __shared__ int lout[NPB * 64];
  __shared__ int lcnt[NPB];
  int t = threadIdx.x;
  int b = blockIdx.x;
  if (t < NPB) lcnt[t] = 0;
  __syncthreads();
  int count = bcur[b]; if (count > BCAP) count = BCAP;
  const int* pk = packed + (b << 11);
  for (int i = t; i < count; i += 256) {
    int p = pk[i];
    int dl = p & 0xff;
    int pos = atomicAdd(&lcnt[dl], 1);
    if (pos < CAP) lout[(dl << 6) + pos] = p >> 8;
  }
  __syncthreads();
  // ssrc/cnt stores: fire-and-forget, drain under the gather phase
  {
    int4* d4 = (int4*)(ssrc + (size_t)b * (NPB * 64));
    const int4* s4 = (const int4*)lout;
    for (int i = t; i < NPB * 16; i += 256) d4[i] = s4[i];
    if (t < NPB) {
      int c = lcnt[t]; if (c > CAP) c = CAP;
      cnt[b * NPB + t] = c;
    }
  }
  // gather phase: subgroup sg = t>>4 handles dl = sg, sg+16, ...
  int sg = t >> 4;
  int l16 = t & 15;
  for (int dl = sg; dl < NPB; dl += 16) {
    int node = b * NPB + dl;
    if (node >= N_NODES) continue;
    int deg = lcnt[dl]; if (deg > CAP) deg = CAP;
    const int* lrow = &lout[dl << 6];
    float4 acc = {0.f, 0.f, 0.f, 0.f};
    for (int base = 0; base < deg; base += 16) {
      int rem = deg - base; if (rem > 16) rem = 16;
      int s[16];
#pragma unroll
      for (int j = 0; j < 16; j++) s[j] = lrow[base + j];  // LDS broadcast
#pragma unroll
      for (int j = 0; j < 16; j++) { if (j >= rem) s[j] = 0; }
      GATHER_BODY_H(xh);
    }
    float dinv = 1.0f / ((float)deg + EPS);
    __half2 p0 = __floats2half2_rn(acc.x * dinv, acc.y * dinv);
    __half2 p1 = __floats2half2_rn(acc.z * dinv, acc.w * dinv);
    uint2 o;
    o.x = *(unsigned int*)&p0; o.y = *(unsigned int*)&p1;
    ((uint2*)(mean1h + (size_t)node * 64))[l16] = o;
  }
}

// ---- MFMA MLP: GEMM1(64x64x128)+relu -> GEMM2(64x128x64), fp16 out ----
__global__ __launch_bounds__(256) void mlp_mfma_kernel(
    const __half* __restrict__ mean1h, const float* __restrict__ W1,
    const float* __restrict__ b1, const float* __restrict__ W2,
    __half* __restrict__ gh) {
  // LDS carve: sM[64][72] 9216B | sW1T[128][72] 18432B | sH[64][136] 17408B
  //            | sW2T[64][136] 17408B = 62464B. sG[64][64] aliases sM.
  __shared__ __align__(16) char smem[62464];
  __half (*sM)[72]    = (__half(*)[72])smem;
  __half (*sW1T)[72]  = (__half(*)[72])(smem + 9216);
  __half (*sH)[136]   = (__half(*)[136])(smem + 27648);
  __half (*sW2T)[136] = (__half(*)[136])(smem + 45056);
  __half (*sG)[64]    = (__half(*)[64])smem;

  int t = threadIdx.x;
  int row0 = blockIdx.x * 64;

  {  // stage mean rows (fp16 as-is): 512 uint4
    const uint4* M4 = (const uint4*)(mean1h + (size_t)row0 * 64);
#pragma unroll
    for (int i = 0; i < 2; i++) {
      int idx = t + 256 * i;
      uint4 v = M4[idx];
      *(uint4*)&sM[idx >> 3][(idx & 7) * 8] = v;
    }
  }
#pragma unroll
  for (int i = 0; i < 8; i++) {  // W1[64][128] f32 -> sW1T[c][k] fp16
    int idx = t + 256 * i;
    int k = idx >> 5, c4 = (idx & 31) * 4;
    float4 w = *(const float4*)(W1 + (size_t)k * 128 + c4);
    sW1T[c4 + 0][k] = __float2half(w.x);
    sW1T[c4 + 1][k] = __float2half(w.y);
    sW1T[c4 + 2][k] = __float2half(w.z);
    sW1T[c4 + 3][k] = __float2half(w.w);
  }
#pragma unroll
  for (int i = 0; i < 8; i++) {  // W2[128][64] f32 -> sW2T[c][k] fp16
    int idx = t + 256 * i;
    int k = idx >> 4, c4 = (idx & 15) * 4;
    float4 w = *(const float4*)(W2 + (size_t)k * 64 + c4);
    sW2T[c4 + 0][k] = __float2half(w.x);
    sW2T[c4 + 1][k] = __float2half(w.y);
    sW2T[c4 + 2][k] = __float2half(w.z);
    sW2T[c4 + 3][k] = __float2half(w.w);
  }
  __syncthreads();

  int l = t & 63, wv = t >> 6;
  int l16 = l & 15, lg = l >> 4;

  {  // GEMM1: wave wv owns col-tiles {2wv,2wv+1} x row-tiles 0..3, K=64
    floatx4 acc[4][2];
#pragma unroll
    for (int tc = 0; tc < 2; tc++) {
      float bias = b1[(2 * wv + tc) * 16 + l16];
#pragma unroll
      for (int tr = 0; tr < 4; tr++)
        acc[tr][tc] = (floatx4){bias, bias, bias, bias};
    }
#pragma unroll
    for (int kb = 0; kb < 2; kb++) {
      half8 a[4], bf[2];
#pragma unroll
      for (int tr = 0; tr < 4; tr++)
        a[tr] = *(const half8*)&sM[tr * 16 + l16][kb * 32 + lg * 8];
#pragma unroll
      for (int tc = 0; tc < 2; tc++)
        bf[tc] = *(const half8*)&sW1T[(2 * wv + tc) * 16 + l16][kb * 32 + lg * 8];
#pragma unroll
      for (int tc = 0; tc < 2; tc++)
#pragma unroll
        for (int tr = 0; tr < 4; tr++)
          acc[tr][tc] = __builtin_amdgcn_mfma_f32_16x16x32_f16(
              a[tr], bf[tc], acc[tr][tc], 0, 0, 0);
    }
#pragma unroll
    for (int tc = 0; tc < 2; tc++)
#pragma unroll
      for (int tr = 0; tr < 4; tr++)
#pragma unroll
        for (int r = 0; r < 4; r++) {
          float h = fmaxf(acc[tr][tc][r], 0.f);
          sH[tr * 16 + lg * 4 + r][(2 * wv + tc) * 16 + l16] = __float2half(h);
        }
  }
  __syncthreads();

  {  // GEMM2: wave wv owns row-tile wv x col-tiles 0..3, K=128
    floatx4 acc[4];
#pragma unroll
    for (int tc = 0; tc < 4; tc++) acc[tc] = (floatx4){0.f, 0.f, 0.f, 0.f};
    half8 a[4];
#pragma unroll
    for (int kb = 0; kb < 4; kb++)
      a[kb] = *(const half8*)&sH[wv * 16 + l16][kb * 32 + lg * 8];
#pragma unroll
    for (int tc = 0; tc < 4; tc++) {
#pragma unroll
      for (int kb = 0; kb < 4; kb++) {
        half8 bf = *(const half8*)&sW2T[tc * 16 + l16][kb * 32 + lg * 8];
        acc[tc] = __builtin_amdgcn_mfma_f32_16x16x32_f16(a[kb], bf, acc[tc], 0, 0, 0);
      }
    }
    // sG aliases sM — sM is dead after GEMM1's closing barrier.
#pragma unroll
    for (int tc = 0; tc < 4; tc++)
#pragma unroll
      for (int r = 0; r < 4; r++)
        sG[wv * 16 + lg * 4 + r][tc * 16 + l16] = __float2half(acc[tc][r]);
  }
  __syncthreads();

  // coalesced copy sG -> gh (8B granules), guard tail rows
#pragma unroll
  for (int i = 0; i < 4; i++) {
    int idx = t + 256 * i;            // 0..1023
    int row = idx >> 4, c4 = (idx & 15) * 4;
    if (row0 + row < N_NODES)
      *(uint2*)(gh + (size_t)(row0 + row) * 64 + c4) = *(uint2*)&sG[row][c4];
  }
}

// ---- Gather 2 + bias + log_softmax (fp16 source, f32 math) ----
__global__ __launch_bounds__(256) void gather2_kernel(
    const __half* __restrict__ gh, const int* __restrict__ cnt,
    const int* __restrict__ ssrc, const float* __restrict__ b2,
    float* __restrict__ out) {
  int t = threadIdx.x;
  int lane = t & 63;
  int sub = lane >> 4;
  int l16 = lane & 15;
  int node = blockIdx.x * 16 + ((t >> 6) << 2) + sub;
  int b = node << 6;
  int e = b + cnt[node];
  float4 acc = {0.f, 0.f, 0.f, 0.f};
  for (int base = b; base < e; base += 16) {
    int rem = e - base; if (rem > 16) rem = 16;
    int s[16];
#pragma unroll
    for (int j = 0; j < 16; j++) s[j] = ssrc[base + j];
#pragma unroll
    for (int j = 0; j < 16; j++) { if (j >= rem) s[j] = 0; }
    GATHER_BODY_H(gh);
  }
  float dinv = 1.0f / ((float)(e - b) + EPS);
  float4 b2v = ((const float4*)b2)[l16];
  float4 val;
  val.x = acc.x * dinv + b2v.x;
  val.y = acc.y * dinv + b2v.y;
  val.z = acc.z * dinv + b2v.z;
  val.w = acc.w * dinv + b2v.w;

  float4 m = val;
#pragma unroll
  for (int o = 8; o > 0; o >>= 1) {
    m.x = fmaxf(m.x, __shfl_xor(m.x, o, 64));
    m.y = fmaxf(m.y, __shfl_xor(m.y, o, 64));
    m.z = fmaxf(m.z, __shfl_xor(m.z, o, 64));
    m.w = fmaxf(m.w, __shfl_xor(m.w, o, 64));
  }
  float mx = fmaxf(fmaxf(m.x, m.z), fmaxf(m.y, m.w));

  float4 ex;
  ex.x = __expf(val.x - mx);
  ex.y = __expf(val.y - mx);
  ex.z = __expf(val.z - mx);
  ex.w = __expf(val.w - mx);
#pragma unroll
  for (int o = 8; o > 0; o >>= 1) {
    ex.x += __shfl_xor(ex.x, o, 64);
    ex.y += __shfl_xor(ex.y, o, 64);
    ex.z += __shfl_xor(ex.z, o, 64);
    ex.w += __shfl_xor(ex.w, o, 64);
  }
  float sm = (ex.x + ex.z) + (ex.y + ex.w);

  float ls = logf(sm);
  float4 o4;
  o4.x = (val.x - mx) - ls;
  o4.y = (val.y - mx) - ls;
  o4.z = (val.z - mx) - ls;
  o4.w = (val.w - mx) - ls;
  ((float4*)(out + (size_t)node * 64))[l16] = o4;
}

extern "C" void kernel_launch(void* const* d_in, const int* in_sizes, int n_in,
                              void* d_out, int out_size, void* d_ws, size_t ws_size,
                              hipStream_t stream) {
  const float* x   = (const float*)d_in[0];
  const int*   src = (const int*)d_in[1];
  const int*   dst = (const int*)d_in[2];
  const float* W1  = (const float*)d_in[3];
  const float* b1  = (const float*)d_in[4];
  const float* W2  = (const float*)d_in[5];
  const float* b2  = (const float*)d_in[6];
  float* out = (float*)d_out;
  int E = in_sizes[1];

  int* bcur   = (int*)d_ws;                         // NBKT
  int* packed = bcur + NBKT;                        // NBKT*BCAP
  int* cnt    = packed + (size_t)NBKT * BCAP;       // NROWS
  int* ssrc   = cnt + NROWS;                        // NROWS*64
  __half* mean1h = (__half*)(ssrc + (size_t)NROWS * 64); // NPAD*64 halves
  __half* xh   = mean1h + (size_t)NPAD * 64;             // NPAD*64 halves
  __half* gh   = xh + (size_t)NPAD * 64;                 // NPAD*64 halves

  hipMemsetAsync(bcur, 0, NBKT * sizeof(int), stream);
  bucketize_kernel<<<(E + CHUNK_A - 1) / CHUNK_A, 256, 0, stream>>>(
      src, dst, bcur, packed, x, xh, E);
  rows_gather1_kernel<<<NBKT, 256, 0, stream>>>(bcur, packed, cnt, ssrc, xh, mean1h);
  mlp_mfma_kernel<<<NPAD / 64, 256, 0, stream>>>(mean1h, W1, b1, W2, gh);
  gather2_kernel<<<N_NODES / 16, 256, 0, stream>>>(gh, cnt, ssrc, b2, out);
}